// Round 13
// baseline (525.014 us; speedup 1.0000x reference)
//
#include <hip/hip_runtime.h>

#define TT 512

typedef _Float16 half8 __attribute__((ext_vector_type(8)));
typedef __attribute__((ext_vector_type(4))) float floatx4;

// raw workgroup barrier (no vmcnt/lgkmcnt drain); LDS FIFO is in-order per CU,
// validated R6-R12 (cross-parity reads stayed bit-exact across 512 steps).
#define BAR() do { __asm__ volatile("" ::: "memory"); \
                   __builtin_amdgcn_s_barrier();      \
                   __asm__ volatile("" ::: "memory"); } while (0)

__device__ __forceinline__ float fast_tanh(float z) {
    const float e = __expf(2.f * z);
    return 1.f - __fdividef(2.f, e + 1.f);
}
__device__ __forceinline__ float f4e(const float4& v, int r) {
    return (r == 0) ? v.x : (r == 1) ? v.y : (r == 2) ? v.z : v.w;
}
__device__ __forceinline__ unsigned pk16(float a, float b) {
    const unsigned ua = __builtin_bit_cast(unsigned short, (_Float16)a);
    const unsigned ub = __builtin_bit_cast(unsigned short, (_Float16)b);
    return ua | (ub << 16);
}

// Two-tile software pipeline over the R10 structure.
// Block = 8 waves = 2 waves/SIMD, handles TWO batch-16 tiles (A=0, B=1).
// Waves 0-3: L0 role, waves 4-7: L1 role — for BOTH tiles (weights shared).
// Interval: issue ds_reads for tile X's next step; compute tile Y's step
// from registers read last interval; raw barrier. Alternate X/Y.
// Read latency+drain hides under the other tile's compute.
// Arithmetic identical to R10 (absmax signature 4.882812e-4).
__global__ void __launch_bounds__(512, 1)
rnn2_pipe(const float* __restrict__ x,
          const float* __restrict__ W_ih0, const float* __restrict__ W_hh0,
          const float* __restrict__ b_ih0, const float* __restrict__ b_hh0,
          const float* __restrict__ W_ih1, const float* __restrict__ W_hh1,
          const float* __restrict__ b_ih1, const float* __restrict__ b_hh1,
          const float* __restrict__ W_fc, const float* __restrict__ b_fc,
          float* __restrict__ out)
{
    __shared__ short h0f[2][2][1024];  // [tile][parity][chunk*512+128q+8n+j]
    __shared__ short h1f[2][2][1024];
    __shared__ float red[2][4][16];    // [tile][wq][n]

    const int tid = threadIdx.x;
    const int lane = tid & 63;
    const int w = tid >> 6;          // 0..7
    const int wq = w & 3;            // M-slice within layer group
    const bool isL0 = (w < 4);
    const int n = lane & 15;
    const int q = lane >> 4;
    const int b0A = blockIdx.x * 32;
    const int b0B = b0A + 16;

    // h1(-1) = 0 at parity 1, both tiles (512 ints each; 512 threads)
    ((int*)&h1f[0][1][0])[tid] = 0;
    ((int*)&h1f[1][1][0])[tid] = 0;

    const int mrow = 16 * wq + n;
    const int m4 = 16 * wq + 4 * q;
    const int rbase = 128 * q + 8 * n;
    const int wbase = (2 * wq + (q >> 1)) * 128 + 8 * n + 4 * (q & 1);

    // ---- weight fragments (shared by both tiles), single fp16 RTNE ----
    half8 wA[2], wB[2];  // L0: A=W_hh0 ; L1: A=W_ih1, B=W_hh1
    auto mkfrag = [&](const float* p, half8& hi) {
#pragma unroll
        for (int j = 0; j < 8; ++j) hi[j] = (_Float16)p[j];
    };
    float4 wih0v = {0, 0, 0, 0}, bv0 = {0, 0, 0, 0}, bv1 = {0, 0, 0, 0}, wfcv = {0, 0, 0, 0};
    if (isL0) {
#pragma unroll
        for (int k = 0; k < 2; ++k) mkfrag(W_hh0 + mrow * 64 + 32 * k + 8 * q, wA[k]);
        wih0v = *(const float4*)(W_ih0 + m4);
        bv0 = *(const float4*)(b_ih0 + m4);
        { float4 t = *(const float4*)(b_hh0 + m4); bv0.x += t.x; bv0.y += t.y; bv0.z += t.z; bv0.w += t.w; }
    } else {
#pragma unroll
        for (int k = 0; k < 2; ++k) {
            mkfrag(W_ih1 + mrow * 64 + 32 * k + 8 * q, wA[k]);
            mkfrag(W_hh1 + mrow * 64 + 32 * k + 8 * q, wB[k]);
        }
        bv1 = *(const float4*)(b_ih1 + m4);
        { float4 t = *(const float4*)(b_hh1 + m4); bv1.x += t.x; bv1.y += t.y; bv1.z += t.z; bv1.w += t.w; }
        wfcv = *(const float4*)(W_fc + m4);
    }

    const float* xpA = x + (long)(b0A + n) * TT;
    const float* xpB = x + (long)(b0B + n) * TT;
    const floatx4 zero4 = {0.f, 0.f, 0.f, 0.f};

    auto epi_write = [&](const floatx4& A, const floatx4& B, short* pf) {
        float h[4];
#pragma unroll
        for (int r = 0; r < 4; ++r) h[r] = fast_tanh(A[r] + B[r]);
        uint2 u;
        u.x = pk16(h[0], h[1]);
        u.y = pk16(h[2], h[3]);
        *(uint2*)&pf[wbase] = u;
    };

    // ---- prologue: L0 writes h0(0) for BOTH tiles -> parity 0 ----
    float xvA = 0.f, xnA = 0.f, xvB = 0.f, xnB = 0.f;
    if (isL0) {
#pragma unroll
        for (int t = 0; t < 2; ++t) {
            const float xv0 = (t == 0) ? xpA[0] : xpB[0];
            float h[4];
#pragma unroll
            for (int r = 0; r < 4; ++r)
                h[r] = fast_tanh(__builtin_fmaf(xv0, f4e(wih0v, r), f4e(bv0, r)));
            uint2 u; u.x = pk16(h[0], h[1]); u.y = pk16(h[2], h[3]);
            *(uint2*)&h0f[t][0][wbase] = u;
        }
        xvA = xpA[1]; xnA = xpA[2];
        xvB = xpB[1]; xnB = xpB[2];
    }
    BAR();

    half8 bA[2], cA[2], bB[2], cB[2];

    // issue reads for tile t's step with h0-parity rp0, h1-parity rp1
    auto readX = [&](int t, int rp0, int rp1, half8* b, half8* c) {
        b[0] = *(const half8*)&h0f[t][rp0][rbase];
        b[1] = *(const half8*)&h0f[t][rp0][rbase + 512];
        if (!isL0) {
            c[0] = *(const half8*)&h1f[t][rp1][rbase];
            c[1] = *(const half8*)&h1f[t][rp1][rbase + 512];
        }
    };
    // compute tile t's step from fragments; wp = s&1 (h0), wp1 = (s-1)&1 (h1)
    auto compX = [&](int t, int wp, int wp1, const half8* b, const half8* c, float xvv) {
        if (isL0) {
            floatx4 aA = {__builtin_fmaf(xvv, wih0v.x, bv0.x), __builtin_fmaf(xvv, wih0v.y, bv0.y),
                          __builtin_fmaf(xvv, wih0v.z, bv0.z), __builtin_fmaf(xvv, wih0v.w, bv0.w)};
            floatx4 aB = zero4;
            aA = __builtin_amdgcn_mfma_f32_16x16x32_f16(wA[0], b[0], aA, 0, 0, 0);
            aB = __builtin_amdgcn_mfma_f32_16x16x32_f16(wA[1], b[1], aB, 0, 0, 0);
            epi_write(aA, aB, &h0f[t][wp][0]);
        } else {
            floatx4 aA = {bv1.x, bv1.y, bv1.z, bv1.w};
            floatx4 aB = zero4;
            aA = __builtin_amdgcn_mfma_f32_16x16x32_f16(wA[0], b[0], aA, 0, 0, 0);
            aB = __builtin_amdgcn_mfma_f32_16x16x32_f16(wB[0], c[0], aB, 0, 0, 0);
            aA = __builtin_amdgcn_mfma_f32_16x16x32_f16(wA[1], b[1], aA, 0, 0, 0);
            aB = __builtin_amdgcn_mfma_f32_16x16x32_f16(wB[1], c[1], aB, 0, 0, 0);
            epi_write(aA, aB, &h1f[t][wp1][0]);
        }
    };

    // t0: prime tile A step 1 (odd: rp0=0, rp1=1)
    readX(0, 0, 1, bA, cA);
    BAR();

    // main loop: s = 1,3,...,509 ; 4 intervals per iteration
    for (int s = 1; s < 511; s += 2) {
        // int1: readB(s); compA(s)   [odd: wp=1, wp1=0]
        readX(1, 0, 1, bB, cB);
        compX(0, 1, 0, bA, cA, xvA);
        if (isL0) { xvA = xnA; xnA = xpA[(s + 2) & (TT - 1)]; }
        BAR();
        // int2: readA(s+1); compB(s)
        readX(0, 1, 0, bA, cA);
        compX(1, 1, 0, bB, cB, xvB);
        if (isL0) { xvB = xnB; xnB = xpB[(s + 2) & (TT - 1)]; }
        BAR();
        // int3: readB(s+1); compA(s+1)  [even: wp=0, wp1=1]
        readX(1, 1, 0, bB, cB);
        compX(0, 0, 1, bA, cA, xvA);
        if (isL0) { xvA = xnA; xnA = xpA[(s + 3) & (TT - 1)]; }
        BAR();
        // int4: readA(s+2); compB(s+1)
        readX(0, 0, 1, bA, cA);
        compX(1, 0, 1, bB, cB, xvB);
        if (isL0) { xvB = xnB; xnB = xpB[(s + 3) & (TT - 1)]; }
        BAR();
    }
    // T1: readB(511); compA(511)  [odd: wp=1, wp1=0]
    readX(1, 0, 1, bB, cB);
    compX(0, 1, 0, bA, cA, xvA);
    BAR();
    // T2: compB(511)
    compX(1, 1, 0, bB, cB, xvB);
    BAR();

    // ---- tails: h1(511) + FC per tile (L1 waves) ----
    if (!isL0) {
#pragma unroll
        for (int t = 0; t < 2; ++t) {
            half8 b[2], c[2];
            b[0] = *(const half8*)&h0f[t][1][rbase];        // h0(511), parity 1
            b[1] = *(const half8*)&h0f[t][1][rbase + 512];
            c[0] = *(const half8*)&h1f[t][0][rbase];        // h1(510), parity 0
            c[1] = *(const half8*)&h1f[t][0][rbase + 512];
            floatx4 aA = {bv1.x, bv1.y, bv1.z, bv1.w};
            floatx4 aB = zero4;
            aA = __builtin_amdgcn_mfma_f32_16x16x32_f16(wA[0], b[0], aA, 0, 0, 0);
            aB = __builtin_amdgcn_mfma_f32_16x16x32_f16(wB[0], c[0], aB, 0, 0, 0);
            aA = __builtin_amdgcn_mfma_f32_16x16x32_f16(wA[1], b[1], aA, 0, 0, 0);
            aB = __builtin_amdgcn_mfma_f32_16x16x32_f16(wB[1], c[1], aB, 0, 0, 0);
            float p = 0.f;
#pragma unroll
            for (int r = 0; r < 4; ++r) {
                const float h = fast_tanh(aA[r] + aB[r]);
                p = __builtin_fmaf(h, f4e(wfcv, r), p);
            }
            p += __shfl_xor(p, 16, 64);
            p += __shfl_xor(p, 32, 64);
            if (lane < 16) red[t][wq][lane] = p;
        }
    }
    __syncthreads();
    if (w == 4 && lane < 16) {
        out[b0A + lane] = red[0][0][lane] + red[0][1][lane] + red[0][2][lane] + red[0][3][lane] + b_fc[0];
        out[b0B + lane] = red[1][0][lane] + red[1][1][lane] + red[1][2][lane] + red[1][3][lane] + b_fc[0];
    }
}

extern "C" void kernel_launch(void* const* d_in, const int* in_sizes, int n_in,
                              void* d_out, int out_size, void* d_ws, size_t ws_size,
                              hipStream_t stream) {
    const float* x     = (const float*)d_in[0];
    const float* W_ih0 = (const float*)d_in[1];
    const float* W_hh0 = (const float*)d_in[2];
    const float* b_ih0 = (const float*)d_in[3];
    const float* b_hh0 = (const float*)d_in[4];
    const float* W_ih1 = (const float*)d_in[5];
    const float* W_hh1 = (const float*)d_in[6];
    const float* b_ih1 = (const float*)d_in[7];
    const float* b_hh1 = (const float*)d_in[8];
    const float* W_fc  = (const float*)d_in[9];
    const float* b_fc  = (const float*)d_in[10];
    float* out = (float*)d_out;

    // 64 blocks x 2 tiles of batch-16 = 2048
    rnn2_pipe<<<64, 512, 0, stream>>>(x, W_ih0, W_hh0, b_ih0, b_hh0,
                                      W_ih1, W_hh1, b_ih1, b_hh1,
                                      W_fc, b_fc, out);
}

// Round 14
// 281.504 us; speedup vs baseline: 1.8650x; 1.8650x over previous
//
#include <hip/hip_runtime.h>

#define TT 512

typedef _Float16 half8 __attribute__((ext_vector_type(8)));
typedef __attribute__((ext_vector_type(4))) float floatx4;

// raw workgroup barrier (no vmcnt/lgkmcnt drain); LDS FIFO is in-order per CU,
// validated R6-R12 (reads issued pre-barrier stay bit-exact vs post-barrier
// overwrites across 512 steps).
#define BAR() do { __asm__ volatile("" ::: "memory"); \
                   __builtin_amdgcn_s_barrier();      \
                   __asm__ volatile("" ::: "memory"); } while (0)

__device__ __forceinline__ float fast_tanh(float z) {
    const float e = __expf(2.f * z);
    return 1.f - __fdividef(2.f, e + 1.f);
}
__device__ __forceinline__ float f4e(const float4& v, int r) {
    return (r == 0) ? v.x : (r == 1) ? v.y : (r == 2) ? v.z : v.w;
}
__device__ __forceinline__ unsigned pk16(float a, float b) {
    const unsigned ua = __builtin_bit_cast(unsigned short, (_Float16)a);
    const unsigned ub = __builtin_bit_cast(unsigned short, (_Float16)b);
    return ua | (ub << 16);
}

// Lag-2 layer pipeline over the R10 grid: 128 blocks x 8 waves (2/SIMD).
// Interval i: waves 0-3 compute h0(i) (own-recurrence read exposed);
//             waves 4-7 compute h1(i-2) using h0(i-2) PREFETCHED during
//             interval i-1 (registers) + h1(i-3) read at interval start
//             (hidden behind the two prefetched-operand MFMAs).
// One raw barrier per interval; h0/h1 double-buffered by parity.
// Arithmetic identical to R10 (absmax signature 4.882812e-4).
__global__ void __launch_bounds__(512, 1)
rnn2_lag(const float* __restrict__ x,
         const float* __restrict__ W_ih0, const float* __restrict__ W_hh0,
         const float* __restrict__ b_ih0, const float* __restrict__ b_hh0,
         const float* __restrict__ W_ih1, const float* __restrict__ W_hh1,
         const float* __restrict__ b_ih1, const float* __restrict__ b_hh1,
         const float* __restrict__ W_fc, const float* __restrict__ b_fc,
         float* __restrict__ out)
{
    __shared__ short h0f[2][1024];  // [parity][chunk*512 + 128q + 8n + j], fp16
    __shared__ short h1f[2][1024];
    __shared__ float red[4][16];

    const int tid = threadIdx.x;
    const int lane = tid & 63;
    const int w = tid >> 6;          // 0..7
    const int wq = w & 3;            // M-slice within the layer group
    const bool isL0 = (w < 4);
    const int n = lane & 15;
    const int q = lane >> 4;
    const int b0 = blockIdx.x * 16;

    // h1(-1) = 0 at parity 1 (read as c by L1 at interval 2)
    ((int*)&h1f[1][0])[tid] = 0;

    const int mrow = 16 * wq + n;
    const int m4 = 16 * wq + 4 * q;
    const int rbase = 128 * q + 8 * n;
    const int wbase = (2 * wq + (q >> 1)) * 128 + 8 * n + 4 * (q & 1);

    // ---- weight fragments, single fp16 RTNE (as R10) ----
    half8 wA[2], wB[2];  // L0: A=W_hh0 ; L1: A=W_ih1, B=W_hh1
    auto mkfrag = [&](const float* p, half8& hi) {
#pragma unroll
        for (int j = 0; j < 8; ++j) hi[j] = (_Float16)p[j];
    };
    float4 wih0v = {0, 0, 0, 0}, bv0 = {0, 0, 0, 0}, bv1 = {0, 0, 0, 0}, wfcv = {0, 0, 0, 0};
    if (isL0) {
#pragma unroll
        for (int k = 0; k < 2; ++k) mkfrag(W_hh0 + mrow * 64 + 32 * k + 8 * q, wA[k]);
        wih0v = *(const float4*)(W_ih0 + m4);
        bv0 = *(const float4*)(b_ih0 + m4);
        { float4 t = *(const float4*)(b_hh0 + m4); bv0.x += t.x; bv0.y += t.y; bv0.z += t.z; bv0.w += t.w; }
    } else {
#pragma unroll
        for (int k = 0; k < 2; ++k) {
            mkfrag(W_ih1 + mrow * 64 + 32 * k + 8 * q, wA[k]);
            mkfrag(W_hh1 + mrow * 64 + 32 * k + 8 * q, wB[k]);
        }
        bv1 = *(const float4*)(b_ih1 + m4);
        { float4 t = *(const float4*)(b_hh1 + m4); bv1.x += t.x; bv1.y += t.y; bv1.z += t.z; bv1.w += t.w; }
        wfcv = *(const float4*)(W_fc + m4);
    }

    const float* xp = x + (long)(b0 + n) * TT;
    const floatx4 zero4 = {0.f, 0.f, 0.f, 0.f};

    auto epi_write = [&](const floatx4& A, const floatx4& B, short* pf) {
        float h[4];
#pragma unroll
        for (int r = 0; r < 4; ++r) h[r] = fast_tanh(A[r] + B[r]);
        uint2 u;
        u.x = pk16(h[0], h[1]);
        u.y = pk16(h[2], h[3]);
        *(uint2*)&pf[wbase] = u;
    };

    // L0 interval: read h0[rp] (exposed, issued first), compute h0, write h0[wp]
    auto stepL0 = [&](int rp, int wp, float xvv) {
        half8 b0v = *(const half8*)&h0f[rp][rbase];
        half8 b1v = *(const half8*)&h0f[rp][rbase + 512];
        floatx4 aA = {__builtin_fmaf(xvv, wih0v.x, bv0.x), __builtin_fmaf(xvv, wih0v.y, bv0.y),
                      __builtin_fmaf(xvv, wih0v.z, bv0.z), __builtin_fmaf(xvv, wih0v.w, bv0.w)};
        floatx4 aB = zero4;
        aA = __builtin_amdgcn_mfma_f32_16x16x32_f16(wA[0], b0v, aA, 0, 0, 0);
        aB = __builtin_amdgcn_mfma_f32_16x16x32_f16(wA[1], b1v, aB, 0, 0, 0);
        epi_write(aA, aB, &h0f[wp][0]);
    };

    // L1 interval: own-recurrence read (c) first, prefetch next h0 (bn),
    // compute on PREFETCHED bp (no wait), then c (hidden), write; bp <- bn.
    auto stepL1 = [&](int rc, int rbn, int wp, half8* bp) {
        half8 c0 = *(const half8*)&h1f[rc][rbase];
        half8 c1 = *(const half8*)&h1f[rc][rbase + 512];
        half8 nb0 = *(const half8*)&h0f[rbn][rbase];
        half8 nb1 = *(const half8*)&h0f[rbn][rbase + 512];
        floatx4 aA = {bv1.x, bv1.y, bv1.z, bv1.w};
        floatx4 aB = zero4;
        aA = __builtin_amdgcn_mfma_f32_16x16x32_f16(wA[0], bp[0], aA, 0, 0, 0);
        aA = __builtin_amdgcn_mfma_f32_16x16x32_f16(wA[1], bp[1], aA, 0, 0, 0);
        aB = __builtin_amdgcn_mfma_f32_16x16x32_f16(wB[0], c0, aB, 0, 0, 0);
        aB = __builtin_amdgcn_mfma_f32_16x16x32_f16(wB[1], c1, aB, 0, 0, 0);
        epi_write(aA, aB, &h1f[wp][0]);
        bp[0] = nb0; bp[1] = nb1;
    };

    // ---- interval 0: L0 writes h0(0) -> parity 0 ----
    float xv = 0.f, xnext = 0.f;
    if (isL0) {
        const float xv0 = xp[0];
        float h[4];
#pragma unroll
        for (int r = 0; r < 4; ++r)
            h[r] = fast_tanh(__builtin_fmaf(xv0, f4e(wih0v, r), f4e(bv0, r)));
        uint2 u; u.x = pk16(h[0], h[1]); u.y = pk16(h[2], h[3]);
        *(uint2*)&h0f[0][wbase] = u;
        xv = xp[1];
        xnext = xp[2];
    }
    BAR();

    // ---- interval 1: L0 h0(1); L1 prefetches h0(0) ----
    half8 bp[2];
    if (isL0) {
        stepL0(0, 1, xv);
        xv = xnext; xnext = xp[3];
    } else {
        bp[0] = *(const half8*)&h0f[0][rbase];
        bp[1] = *(const half8*)&h0f[0][rbase + 512];
    }
    BAR();

    // ---- main loop: intervals i = 2..511 (pairs) ----
    // interval i: L0 computes h0(i); L1 computes h1(i-2), prefetches h0(i-1)
    for (int i = 2; i < 511; i += 2) {
        // P = 0
        if (isL0) {
            stepL0(1, 0, xv);
            xv = xnext; xnext = xp[(i + 2) & (TT - 1)];
        } else {
            stepL1(1, 1, 0, bp);
        }
        BAR();
        // P = 1
        if (isL0) {
            stepL0(0, 1, xv);
            xv = xnext; xnext = xp[(i + 3) & (TT - 1)];
        } else {
            stepL1(0, 0, 1, bp);
        }
        BAR();
    }

    // ---- tail interval 512: L1 computes h1(510), prefetches h0(511) ----
    if (!isL0) stepL1(1, 1, 0, bp);
    BAR();

    // ---- tail interval 513: L1 computes h1(511) in regs + FC dot ----
    float p = 0.f;
    if (!isL0) {
        half8 c0 = *(const half8*)&h1f[0][rbase];        // h1(510), parity 0
        half8 c1 = *(const half8*)&h1f[0][rbase + 512];
        floatx4 aA = {bv1.x, bv1.y, bv1.z, bv1.w};
        floatx4 aB = zero4;
        aA = __builtin_amdgcn_mfma_f32_16x16x32_f16(wA[0], bp[0], aA, 0, 0, 0);  // h0(511)
        aA = __builtin_amdgcn_mfma_f32_16x16x32_f16(wA[1], bp[1], aA, 0, 0, 0);
        aB = __builtin_amdgcn_mfma_f32_16x16x32_f16(wB[0], c0, aB, 0, 0, 0);
        aB = __builtin_amdgcn_mfma_f32_16x16x32_f16(wB[1], c1, aB, 0, 0, 0);
#pragma unroll
        for (int r = 0; r < 4; ++r) {
            const float h = fast_tanh(aA[r] + aB[r]);
            p = __builtin_fmaf(h, f4e(wfcv, r), p);
        }
        p += __shfl_xor(p, 16, 64);
        p += __shfl_xor(p, 32, 64);
        if (lane < 16) red[wq][lane] = p;
    }
    __syncthreads();
    if (w == 4 && lane < 16)
        out[b0 + lane] = red[0][lane] + red[1][lane] + red[2][lane] + red[3][lane] + b_fc[0];
}

extern "C" void kernel_launch(void* const* d_in, const int* in_sizes, int n_in,
                              void* d_out, int out_size, void* d_ws, size_t ws_size,
                              hipStream_t stream) {
    const float* x     = (const float*)d_in[0];
    const float* W_ih0 = (const float*)d_in[1];
    const float* W_hh0 = (const float*)d_in[2];
    const float* b_ih0 = (const float*)d_in[3];
    const float* b_hh0 = (const float*)d_in[4];
    const float* W_ih1 = (const float*)d_in[5];
    const float* W_hh1 = (const float*)d_in[6];
    const float* b_ih1 = (const float*)d_in[7];
    const float* b_hh1 = (const float*)d_in[8];
    const float* W_fc  = (const float*)d_in[9];
    const float* b_fc  = (const float*)d_in[10];
    float* out = (float*)d_out;

    rnn2_lag<<<128, 512, 0, stream>>>(x, W_ih0, W_hh0, b_ih0, b_hh0,
                                      W_ih1, W_hh1, b_ih1, b_hh1,
                                      W_fc, b_fc, out);
}